// Round 1
// baseline (15281.201 us; speedup 1.0000x reference)
//
#include <hip/hip_runtime.h>
#include <hip/hip_bf16.h>

#define B_ 2
#define L_ 2048
#define DIM_ 2048
#define H_ 16
#define KVH_ 4
#define HD_ 128
#define E_ 8
#define HID_ 8192
#define T_ (B_*L_)      // 4096
#define EPS_ 1e-6f
#define CAP_ 8704       // 8192 real slots + 8*64 pad

// ---------------- RMSNorm ----------------
__global__ __launch_bounds__(256) void rmsnorm_kernel(const float* __restrict__ x,
    const float* __restrict__ w, float* __restrict__ y)
{
    int row = blockIdx.x;
    const float4* xr = (const float4*)(x + (size_t)row * DIM_);
    float ss = 0.f;
#pragma unroll
    for (int i = 0; i < DIM_/4/256; i++) {
        float4 v = xr[threadIdx.x + i*256];
        ss += v.x*v.x + v.y*v.y + v.z*v.z + v.w*v.w;
    }
#pragma unroll
    for (int off = 32; off; off >>= 1) ss += __shfl_down(ss, off);
    __shared__ float red[4];
    __shared__ float sinv;
    int lane = threadIdx.x & 63, wid = threadIdx.x >> 6;
    if (lane == 0) red[wid] = ss;
    __syncthreads();
    if (threadIdx.x == 0)
        sinv = rsqrtf((red[0]+red[1]+red[2]+red[3]) * (1.0f/DIM_) + EPS_);
    __syncthreads();
    float inv = sinv;
    const float4* wr = (const float4*)w;
    float4* yr = (float4*)(y + (size_t)row * DIM_);
#pragma unroll
    for (int i = 0; i < DIM_/4/256; i++) {
        int idx = threadIdx.x + i*256;
        float4 v = xr[idx]; float4 g = wr[idx];
        float4 o; o.x=v.x*inv*g.x; o.y=v.y*inv*g.y; o.z=v.z*inv*g.z; o.w=v.w*inv*g.w;
        yr[idx] = o;
    }
}

// ---------------- generic fp32 GEMM: C = A(MxK) @ B(KxN) [+ addend] ----------------
__global__ __launch_bounds__(256) void gemm_f32(const float* __restrict__ A,
    const float* __restrict__ Bm, float* __restrict__ C,
    int M, int N, int K, const float* __restrict__ addend)
{
    __shared__ float As[16][64];
    __shared__ float Bs[16][64];
    int n0 = blockIdx.x * 64, m0 = blockIdx.y * 64;
    int tid = threadIdx.x;
    int tx = tid & 15, ty = tid >> 4;
    int arow = tid >> 2, acol = (tid & 3) << 2;
    int brow = tid >> 4, bcol = (tid & 15) << 2;
    const float* aptr = A + (size_t)(m0 + arow) * K + acol;
    const float* bptr = Bm + (size_t)brow * N + n0 + bcol;
    float acc[4][4] = {};
    for (int k0 = 0; k0 < K; k0 += 16) {
        float4 av = *(const float4*)(aptr + k0);
        float4 bv = *(const float4*)(bptr + (size_t)k0 * N);
        __syncthreads();
        As[acol+0][arow] = av.x; As[acol+1][arow] = av.y;
        As[acol+2][arow] = av.z; As[acol+3][arow] = av.w;
        *(float4*)&Bs[brow][bcol] = bv;
        __syncthreads();
#pragma unroll
        for (int kk = 0; kk < 16; kk++) {
            float4 a = *(const float4*)&As[kk][ty<<2];
            float4 b = *(const float4*)&Bs[kk][tx<<2];
            acc[0][0]+=a.x*b.x; acc[0][1]+=a.x*b.y; acc[0][2]+=a.x*b.z; acc[0][3]+=a.x*b.w;
            acc[1][0]+=a.y*b.x; acc[1][1]+=a.y*b.y; acc[1][2]+=a.y*b.z; acc[1][3]+=a.y*b.w;
            acc[2][0]+=a.z*b.x; acc[2][1]+=a.z*b.y; acc[2][2]+=a.z*b.z; acc[2][3]+=a.z*b.w;
            acc[3][0]+=a.w*b.x; acc[3][1]+=a.w*b.y; acc[3][2]+=a.w*b.z; acc[3][3]+=a.w*b.w;
        }
    }
    int row = m0 + (ty<<2), col = n0 + (tx<<2);
#pragma unroll
    for (int i = 0; i < 4; i++) {
        float4 r; r.x=acc[i][0]; r.y=acc[i][1]; r.z=acc[i][2]; r.w=acc[i][3];
        if (addend) {
            float4 ad = *(const float4*)(addend + (size_t)(row+i)*N + col);
            r.x+=ad.x; r.y+=ad.y; r.z+=ad.z; r.w+=ad.w;
        }
        *(float4*)(C + (size_t)(row+i)*N + col) = r;
    }
}

// ---------------- RoPE (in place) ----------------
__global__ __launch_bounds__(256) void rope_kernel(float* __restrict__ p, int nheads)
{
    int idx = blockIdx.x * 256 + threadIdx.x;
    int total = T_ * nheads * (HD_/2);
    if (idx >= total) return;
    int i = idx & 63;
    int th = idx >> 6;
    int head = th % nheads;
    int t = th / nheads;
    int pos = t & (L_-1);
    float inv = powf(10000.0f, -(float)(2*i) / (float)HD_);
    float ang = (float)pos * inv;
    float s, c;
    sincosf(ang, &s, &c);
    float* q = p + (size_t)t * nheads * HD_ + head * HD_;
    float x1 = q[i], x2 = q[i+64];
    q[i]    = x1*c - x2*s;
    q[i+64] = x2*c + x1*s;
}

// ---------------- flash attention (causal, GQA), fp32 ----------------
// grid: (L/32, H, B). O may alias Q (each block writes only rows it alone reads).
__global__ __launch_bounds__(256) void attn_kernel(const float* __restrict__ q,
    const float* __restrict__ k, const float* __restrict__ v, float* __restrict__ o)
{
    int qt = blockIdx.x;
    int hh = blockIdx.y;
    int b  = blockIdx.z;
    int kvh = hh / (H_/KVH_);
    __shared__ float Qs[32][HD_];
    __shared__ float Ks[32][HD_];
    __shared__ float Vs[32][HD_];
    __shared__ float Ps[32][33];
    __shared__ float mrow[32], lrow[32], arow[32];
    int tid = threadIdx.x;
    int tx = tid & 15, ty = tid >> 4;
    const float* qbase = q + ((size_t)(b*L_ + qt*32))*DIM_ + hh*HD_;
#pragma unroll
    for (int w = 0; w < 4; w++) {
        int idx = tid + w*256;
        int r = idx >> 5, c4 = (idx & 31) << 2;
        *(float4*)&Qs[r][c4] = *(const float4*)(qbase + (size_t)r*DIM_ + c4);
    }
    if (tid < 32) { mrow[tid] = -INFINITY; lrow[tid] = 0.f; }
    float oacc[2][8] = {};
    const float scale = 0.08838834764831845f;
    for (int kt = 0; kt <= qt; kt++) {
        __syncthreads();
        const float* kbase = k + ((size_t)(b*L_ + kt*32))*(KVH_*HD_) + kvh*HD_;
        const float* vbase = v + ((size_t)(b*L_ + kt*32))*(KVH_*HD_) + kvh*HD_;
#pragma unroll
        for (int w = 0; w < 4; w++) {
            int idx = tid + w*256;
            int r = idx >> 5, c4 = (idx & 31) << 2;
            *(float4*)&Ks[r][c4] = *(const float4*)(kbase + (size_t)r*(KVH_*HD_) + c4);
            *(float4*)&Vs[r][c4] = *(const float4*)(vbase + (size_t)r*(KVH_*HD_) + c4);
        }
        __syncthreads();
        float s00=0,s01=0,s10=0,s11=0;
#pragma unroll
        for (int d4 = 0; d4 < HD_; d4 += 4) {
            float4 a0 = *(const float4*)&Qs[(ty<<1)+0][d4];
            float4 a1 = *(const float4*)&Qs[(ty<<1)+1][d4];
            float4 b0 = *(const float4*)&Ks[(tx<<1)+0][d4];
            float4 b1 = *(const float4*)&Ks[(tx<<1)+1][d4];
            s00 += a0.x*b0.x + a0.y*b0.y + a0.z*b0.z + a0.w*b0.w;
            s01 += a0.x*b1.x + a0.y*b1.y + a0.z*b1.z + a0.w*b1.w;
            s10 += a1.x*b0.x + a1.y*b0.y + a1.z*b0.z + a1.w*b0.w;
            s11 += a1.x*b1.x + a1.y*b1.y + a1.z*b1.z + a1.w*b1.w;
        }
        int qg0 = qt*32 + (ty<<1), kg0 = kt*32 + (tx<<1);
        Ps[(ty<<1)  ][(tx<<1)  ] = (kg0   <= qg0  ) ? s00*scale : -INFINITY;
        Ps[(ty<<1)  ][(tx<<1)+1] = (kg0+1 <= qg0  ) ? s01*scale : -INFINITY;
        Ps[(ty<<1)+1][(tx<<1)  ] = (kg0   <= qg0+1) ? s10*scale : -INFINITY;
        Ps[(ty<<1)+1][(tx<<1)+1] = (kg0+1 <= qg0+1) ? s11*scale : -INFINITY;
        __syncthreads();
        if (tid < 32) {
            int r = tid;
            float mold = mrow[r];
            float mnew = mold;
#pragma unroll
            for (int c = 0; c < 32; c++) mnew = fmaxf(mnew, Ps[r][c]);
            float alpha = expf(mold - mnew);
            float lsum = lrow[r] * alpha;
#pragma unroll
            for (int c = 0; c < 32; c++) {
                float pv = expf(Ps[r][c] - mnew);
                Ps[r][c] = pv;
                lsum += pv;
            }
            mrow[r] = mnew; lrow[r] = lsum; arow[r] = alpha;
        }
        __syncthreads();
        float al0 = arow[(ty<<1)], al1 = arow[(ty<<1)+1];
#pragma unroll
        for (int j = 0; j < 8; j++) { oacc[0][j] *= al0; oacc[1][j] *= al1; }
#pragma unroll
        for (int kk = 0; kk < 32; kk++) {
            float p0 = Ps[(ty<<1)][kk], p1 = Ps[(ty<<1)+1][kk];
            float4 v0 = *(const float4*)&Vs[kk][(tx<<3)];
            float4 v1 = *(const float4*)&Vs[kk][(tx<<3)+4];
            oacc[0][0]+=p0*v0.x; oacc[0][1]+=p0*v0.y; oacc[0][2]+=p0*v0.z; oacc[0][3]+=p0*v0.w;
            oacc[0][4]+=p0*v1.x; oacc[0][5]+=p0*v1.y; oacc[0][6]+=p0*v1.z; oacc[0][7]+=p0*v1.w;
            oacc[1][0]+=p1*v0.x; oacc[1][1]+=p1*v0.y; oacc[1][2]+=p1*v0.z; oacc[1][3]+=p1*v0.w;
            oacc[1][4]+=p1*v1.x; oacc[1][5]+=p1*v1.y; oacc[1][6]+=p1*v1.z; oacc[1][7]+=p1*v1.w;
        }
    }
    float linv0 = 1.0f / lrow[(ty<<1)];
    float linv1 = 1.0f / lrow[(ty<<1)+1];
    float* obase = o + ((size_t)(b*L_ + qt*32))*DIM_ + hh*HD_;
    float4 r0 = {oacc[0][0]*linv0, oacc[0][1]*linv0, oacc[0][2]*linv0, oacc[0][3]*linv0};
    float4 r1 = {oacc[0][4]*linv0, oacc[0][5]*linv0, oacc[0][6]*linv0, oacc[0][7]*linv0};
    float4 r2 = {oacc[1][0]*linv1, oacc[1][1]*linv1, oacc[1][2]*linv1, oacc[1][3]*linv1};
    float4 r3 = {oacc[1][4]*linv1, oacc[1][5]*linv1, oacc[1][6]*linv1, oacc[1][7]*linv1};
    *(float4*)(obase + (size_t)((ty<<1)  )*DIM_ + (tx<<3)    ) = r0;
    *(float4*)(obase + (size_t)((ty<<1)  )*DIM_ + (tx<<3) + 4) = r1;
    *(float4*)(obase + (size_t)((ty<<1)+1)*DIM_ + (tx<<3)    ) = r2;
    *(float4*)(obase + (size_t)((ty<<1)+1)*DIM_ + (tx<<3) + 4) = r3;
}

// ---------------- router: logits -> softmax -> top2 -> counts ----------------
__global__ __launch_bounds__(256) void router_kernel(const float* __restrict__ hn,
    const float* __restrict__ rw, float* __restrict__ topw, int* __restrict__ topi,
    int* __restrict__ counts)
{
    int t = blockIdx.x;
    const float* xr = hn + (size_t)t * DIM_;
    float acc[8] = {};
    for (int d = threadIdx.x; d < DIM_; d += 256) {
        float xv = xr[d];
        const float* r = rw + (size_t)d * E_;
        float4 r0 = *(const float4*)r;
        float4 r1 = *(const float4*)(r+4);
        acc[0]+=xv*r0.x; acc[1]+=xv*r0.y; acc[2]+=xv*r0.z; acc[3]+=xv*r0.w;
        acc[4]+=xv*r1.x; acc[5]+=xv*r1.y; acc[6]+=xv*r1.z; acc[7]+=xv*r1.w;
    }
#pragma unroll
    for (int off = 32; off; off >>= 1)
#pragma unroll
        for (int e = 0; e < 8; e++) acc[e] += __shfl_down(acc[e], off);
    __shared__ float red[4][8];
    int lane = threadIdx.x & 63, wid = threadIdx.x >> 6;
    if (lane == 0)
        for (int e = 0; e < 8; e++) red[wid][e] = acc[e];
    __syncthreads();
    if (threadIdx.x == 0) {
        float lg[8];
        for (int e = 0; e < 8; e++) lg[e] = red[0][e]+red[1][e]+red[2][e]+red[3][e];
        float mx = lg[0];
        for (int e = 1; e < 8; e++) mx = fmaxf(mx, lg[e]);
        float p[8]; float se = 0.f;
        for (int e = 0; e < 8; e++) { p[e] = expf(lg[e]-mx); se += p[e]; }
        for (int e = 0; e < 8; e++) p[e] /= se;
        int i0 = 0;
        for (int e = 1; e < 8; e++) if (p[e] > p[i0]) i0 = e;
        int i1 = -1;
        for (int e = 0; e < 8; e++) if (e != i0 && (i1 < 0 || p[e] > p[i1])) i1 = e;
        float w0 = p[i0], w1 = p[i1], s2 = w0 + w1;
        topi[t*2] = i0; topi[t*2+1] = i1;
        topw[t*2] = w0/s2; topw[t*2+1] = w1/s2;
        atomicAdd(&counts[i0], 1); atomicAdd(&counts[i1], 1);
    }
}

__global__ void scan_kernel(const int* __restrict__ counts, int* __restrict__ offs,
                            int* __restrict__ cursor)
{
    if (threadIdx.x == 0 && blockIdx.x == 0) {
        int o = 0;
        for (int e = 0; e < E_; e++) {
            offs[e] = o; cursor[e] = o;
            o += (counts[e] + 63) & ~63;
        }
        offs[E_] = o;
    }
}

__global__ __launch_bounds__(256) void scatter_kernel(const int* __restrict__ topi,
    const float* __restrict__ topw, int* __restrict__ cursor,
    int* __restrict__ rowmap, float* __restrict__ roww)
{
    int t = blockIdx.x*256 + threadIdx.x;
    if (t >= T_) return;
    for (int kk = 0; kk < 2; kk++) {
        int e = topi[t*2+kk];
        int slot = atomicAdd(&cursor[e], 1);
        rowmap[slot] = t; roww[slot] = topw[t*2+kk];
    }
}

// ---------------- MoE GEMM1: hmid[slot] = silu(hn[tok] @ w1[e]) ----------------
__global__ __launch_bounds__(256) void moe_gemm1(const float* __restrict__ hn,
    const float* __restrict__ w1, __hip_bfloat16* __restrict__ hmid,
    const int* __restrict__ rowmap, const int* __restrict__ offs)
{
    int n0 = blockIdx.x * 64;
    int m0 = blockIdx.y * 64;
    if (m0 >= offs[E_]) return;
    int e = 0;
    while (e < E_ && m0 >= offs[e+1]) e++;
    __shared__ float As[16][64];
    __shared__ float Bs[16][64];
    int tid = threadIdx.x, tx = tid & 15, ty = tid >> 4;
    int arow = tid >> 2, acol = (tid & 3) << 2;
    int brow = tid >> 4, bcol = (tid & 15) << 2;
    int tok = rowmap[m0 + arow];
    const float* aptr = (tok >= 0) ? (hn + (size_t)tok*DIM_ + acol) : nullptr;
    const float* bptr = w1 + (size_t)e*DIM_*HID_ + (size_t)brow*HID_ + n0 + bcol;
    float acc[4][4] = {};
    for (int k0 = 0; k0 < DIM_; k0 += 16) {
        float4 av = aptr ? *(const float4*)(aptr + k0) : make_float4(0.f,0.f,0.f,0.f);
        float4 bv = *(const float4*)(bptr + (size_t)k0*HID_);
        __syncthreads();
        As[acol+0][arow]=av.x; As[acol+1][arow]=av.y; As[acol+2][arow]=av.z; As[acol+3][arow]=av.w;
        *(float4*)&Bs[brow][bcol] = bv;
        __syncthreads();
#pragma unroll
        for (int kk = 0; kk < 16; kk++) {
            float4 a = *(const float4*)&As[kk][ty<<2];
            float4 b = *(const float4*)&Bs[kk][tx<<2];
            acc[0][0]+=a.x*b.x; acc[0][1]+=a.x*b.y; acc[0][2]+=a.x*b.z; acc[0][3]+=a.x*b.w;
            acc[1][0]+=a.y*b.x; acc[1][1]+=a.y*b.y; acc[1][2]+=a.y*b.z; acc[1][3]+=a.y*b.w;
            acc[2][0]+=a.z*b.x; acc[2][1]+=a.z*b.y; acc[2][2]+=a.z*b.z; acc[2][3]+=a.z*b.w;
            acc[3][0]+=a.w*b.x; acc[3][1]+=a.w*b.y; acc[3][2]+=a.w*b.z; acc[3][3]+=a.w*b.w;
        }
    }
    int row = m0 + (ty<<2), col = n0 + (tx<<2);
#pragma unroll
    for (int i = 0; i < 4; i++) {
        __hip_bfloat16* hp = hmid + (size_t)(row+i)*HID_ + col;
#pragma unroll
        for (int j = 0; j < 4; j++) {
            float vv = acc[i][j];
            vv = vv / (1.f + expf(-vv));
            hp[j] = __float2bfloat16(vv);
        }
    }
}

// ---------------- MoE GEMM2: out[tok] += roww[slot] * (hmid[slot] @ w2[e]) ----------------
__global__ __launch_bounds__(256) void moe_gemm2(const __hip_bfloat16* __restrict__ hmid,
    const float* __restrict__ w2, float* __restrict__ out,
    const int* __restrict__ rowmap, const float* __restrict__ roww,
    const int* __restrict__ offs)
{
    int n0 = blockIdx.x * 64;
    int m0 = blockIdx.y * 64;
    if (m0 >= offs[E_]) return;
    int e = 0;
    while (e < E_ && m0 >= offs[e+1]) e++;
    __shared__ float As[16][64];
    __shared__ float Bs[16][64];
    int tid = threadIdx.x, tx = tid & 15, ty = tid >> 4;
    int arow = tid >> 2, acol = (tid & 3) << 2;
    int brow = tid >> 4, bcol = (tid & 15) << 2;
    const __hip_bfloat16* aptr = hmid + (size_t)(m0 + arow)*HID_ + acol;
    const float* bptr = w2 + (size_t)e*HID_*DIM_ + (size_t)brow*DIM_ + n0 + bcol;
    float acc[4][4] = {};
    for (int k0 = 0; k0 < HID_; k0 += 16) {
        ushort4 u = *(const ushort4*)(aptr + k0);
        float4 bv = *(const float4*)(bptr + (size_t)k0*DIM_);
        float a0 = __uint_as_float((unsigned)u.x << 16);
        float a1 = __uint_as_float((unsigned)u.y << 16);
        float a2 = __uint_as_float((unsigned)u.z << 16);
        float a3 = __uint_as_float((unsigned)u.w << 16);
        __syncthreads();
        As[acol+0][arow]=a0; As[acol+1][arow]=a1; As[acol+2][arow]=a2; As[acol+3][arow]=a3;
        *(float4*)&Bs[brow][bcol] = bv;
        __syncthreads();
#pragma unroll
        for (int kk = 0; kk < 16; kk++) {
            float4 a = *(const float4*)&As[kk][ty<<2];
            float4 b = *(const float4*)&Bs[kk][tx<<2];
            acc[0][0]+=a.x*b.x; acc[0][1]+=a.x*b.y; acc[0][2]+=a.x*b.z; acc[0][3]+=a.x*b.w;
            acc[1][0]+=a.y*b.x; acc[1][1]+=a.y*b.y; acc[1][2]+=a.y*b.z; acc[1][3]+=a.y*b.w;
            acc[2][0]+=a.z*b.x; acc[2][1]+=a.z*b.y; acc[2][2]+=a.z*b.z; acc[2][3]+=a.z*b.w;
            acc[3][0]+=a.w*b.x; acc[3][1]+=a.w*b.y; acc[3][2]+=a.w*b.z; acc[3][3]+=a.w*b.w;
        }
    }
    int col = n0 + (tx<<2);
#pragma unroll
    for (int i = 0; i < 4; i++) {
        int slot = m0 + (ty<<2) + i;
        int tok = rowmap[slot];
        if (tok >= 0) {
            float wgt = roww[slot];
            float* op = out + (size_t)tok*DIM_ + col;
            atomicAdd(&op[0], acc[i][0]*wgt);
            atomicAdd(&op[1], acc[i][1]*wgt);
            atomicAdd(&op[2], acc[i][2]*wgt);
            atomicAdd(&op[3], acc[i][3]*wgt);
        }
    }
}

__global__ __launch_bounds__(256) void copy_kernel(const float* __restrict__ a,
    float* __restrict__ b, int n4)
{
    int i = blockIdx.x*256 + threadIdx.x;
    if (i < n4) ((float4*)b)[i] = ((const float4*)a)[i];
}

extern "C" void kernel_launch(void* const* d_in, const int* in_sizes, int n_in,
                              void* d_out, int out_size, void* d_ws, size_t ws_size,
                              hipStream_t stream)
{
    (void)in_sizes; (void)n_in; (void)out_size; (void)ws_size;
    const float* x   = (const float*)d_in[0];
    const float* n1w = (const float*)d_in[1];
    const float* wq  = (const float*)d_in[2];
    const float* wk  = (const float*)d_in[3];
    const float* wv  = (const float*)d_in[4];
    const float* wo  = (const float*)d_in[5];
    const float* n2w = (const float*)d_in[6];
    const float* rw  = (const float*)d_in[7];
    const float* w1  = (const float*)d_in[8];
    const float* w2  = (const float*)d_in[9];
    float* out = (float*)d_out;

    char* ws = (char*)d_ws;
    size_t off = 0;
    auto alloc = [&](size_t bytes) -> void* {
        void* p = ws + off;
        off += (bytes + 255) & ~(size_t)255;
        return p;
    };
    float* xn     = (float*)alloc((size_t)T_*DIM_*4);
    float* q      = (float*)alloc((size_t)T_*DIM_*4);
    float* kbuf   = (float*)alloc((size_t)T_*KVH_*HD_*4);
    float* vbuf   = (float*)alloc((size_t)T_*KVH_*HD_*4);
    float* h      = (float*)alloc((size_t)T_*DIM_*4);
    float* hn     = (float*)alloc((size_t)T_*DIM_*4);
    float* topw   = (float*)alloc((size_t)T_*2*4);
    int*   topi   = (int*)  alloc((size_t)T_*2*4);
    int*   counts = (int*)  alloc(E_*4);
    int*   offs   = (int*)  alloc((E_+1)*4);
    int*   cursor = (int*)  alloc(E_*4);
    int*   rowmap = (int*)  alloc((size_t)CAP_*4);
    float* roww   = (float*)alloc((size_t)CAP_*4);
    __hip_bfloat16* hmid = (__hip_bfloat16*)alloc((size_t)CAP_*HID_*2);

    hipMemsetAsync(counts, 0, E_*4, stream);
    hipMemsetAsync(rowmap, 0xFF, (size_t)CAP_*4, stream);

    rmsnorm_kernel<<<T_, 256, 0, stream>>>(x, n1w, xn);
    gemm_f32<<<dim3(DIM_/64, T_/64), 256, 0, stream>>>(xn, wq, q,    T_, DIM_, DIM_, nullptr);
    gemm_f32<<<dim3((KVH_*HD_)/64, T_/64), 256, 0, stream>>>(xn, wk, kbuf, T_, KVH_*HD_, DIM_, nullptr);
    gemm_f32<<<dim3((KVH_*HD_)/64, T_/64), 256, 0, stream>>>(xn, wv, vbuf, T_, KVH_*HD_, DIM_, nullptr);
    rope_kernel<<<(T_*H_*(HD_/2)+255)/256, 256, 0, stream>>>(q, H_);
    rope_kernel<<<(T_*KVH_*(HD_/2)+255)/256, 256, 0, stream>>>(kbuf, KVH_);
    attn_kernel<<<dim3(L_/32, H_, B_), 256, 0, stream>>>(q, kbuf, vbuf, q);
    gemm_f32<<<dim3(DIM_/64, T_/64), 256, 0, stream>>>(q, wo, h, T_, DIM_, DIM_, x);
    rmsnorm_kernel<<<T_, 256, 0, stream>>>(h, n2w, hn);
    router_kernel<<<T_, 256, 0, stream>>>(hn, rw, topw, topi, counts);
    scan_kernel<<<1, 64, 0, stream>>>(counts, offs, cursor);
    scatter_kernel<<<(T_+255)/256, 256, 0, stream>>>(topi, topw, cursor, rowmap, roww);
    moe_gemm1<<<dim3(HID_/64, CAP_/64), 256, 0, stream>>>(hn, w1, hmid, rowmap, offs);
    copy_kernel<<<((T_*DIM_/4)+255)/256, 256, 0, stream>>>(h, out, T_*DIM_/4);
    moe_gemm2<<<dim3(DIM_/64, CAP_/64), 256, 0, stream>>>(hmid, w2, out, rowmap, roww, offs);
}